// Round 6
// baseline (620.355 us; speedup 1.0000x reference)
//
#include <hip/hip_runtime.h>
#include <hip/hip_bf16.h>

#define NQ 4096
#define NK 8192
#define DQK 256
#define DA 64
#define NH 4
#define DOUT 256
#define KSPLIT 16
#define KLEN (NK / KSPLIT)   // 512 keys per split
#define NQT (NQ / 32)        // 128 q-tiles of 32
#define NSUP 4               // split-groups surviving to combine (16/4 waves)
#define LOG2E 1.44269504088896340736f
#define QSCALE (0.125f * LOG2E)   // 1/sqrt(64) * log2(e), folded into Qp

typedef __attribute__((ext_vector_type(8))) short bf16x8;
typedef __attribute__((ext_vector_type(4))) float f32x4;
typedef __attribute__((ext_vector_type(4))) _Float16 f16x4;
typedef __attribute__((ext_vector_type(8))) _Float16 f16x8;

__device__ inline unsigned short f2bf(float f) {
  union { float f; unsigned u; } v; v.f = f;
  unsigned r = v.u + 0x7fff + ((v.u >> 16) & 1);  // RNE
  return (unsigned short)(r >> 16);
}

// ---------------------------------------------------------------------------
// 1. mask (int32 NQ x NK) -> TRANSPOSED bitmask bitsT[word32][row] (4 MB).
//    attn then reads 16 consecutive rows' words as one 64B segment.
// ---------------------------------------------------------------------------
__global__ __launch_bounds__(256) void maskbits_kernel(
    const int* __restrict__ mask, unsigned* __restrict__ bitsT) {
  const int NW = 8192 * 4;                       // total waves
  int wid = blockIdx.x * 4 + (threadIdx.x >> 6);
  int lane = threadIdx.x & 63;
  for (int j = 0; j < 2; ++j) {
    int v[8];
#pragma unroll
    for (int u = 0; u < 8; ++u) {
      int c = wid + (j * 8 + u) * NW;   // u64 chunk id: row = c>>7, ch = c&127
      v[u] = mask[(size_t)(c >> 7) * NK + (c & 127) * 64 + lane];
    }
#pragma unroll
    for (int u = 0; u < 8; ++u) {
      unsigned long long b = __ballot(v[u] != 0);
      int c = wid + (j * 8 + u) * NW;
      int n = c >> 7, ch = c & 127;
      if (lane == 0)  bitsT[(size_t)(2 * ch) * NQ + n] = (unsigned)b;
      if (lane == 32) bitsT[(size_t)(2 * ch + 1) * NQ + n] = (unsigned)(b >> 32);
    }
  }
}

// ---------------------------------------------------------------------------
// 2. projections: Q = xQ@Wq[h] * QSCALE -> Qp[h][n][d] bf16 (scale folded)
//                 K = xK@Wk[h] -> Kp[h][m][d] bf16
//                 V -> Vf f16 in MFMA A-FRAGMENT-LINEAR order: the proj
//                 accumulator lane content (4 consecutive keys of one d,
//                 lane = quad*16+n16) IS the PV A-frag, so store it
//                 contiguously per (tile32,kr,dt): 512B coalesced stores,
//                 512B coalesced loads in attn.
// ---------------------------------------------------------------------------
__global__ __launch_bounds__(256) void proj_kernel(
    const float* __restrict__ xQ, const float* __restrict__ xK,
    const float* __restrict__ Wq, const float* __restrict__ Wk,
    const float* __restrict__ Wv,
    unsigned short* __restrict__ Qp, unsigned short* __restrict__ Kp,
    _Float16* __restrict__ Vf) {
  __shared__ __align__(16) unsigned short Wt[64][264];  // Wt[d][c], padded

  int b = blockIdx.x;
  int proj, h, rb;
  if (b < 64)        { proj = 0; h = b >> 4;  rb = b & 15; }
  else if (b < 192)  { proj = 1; b -= 64;  h = b >> 5; rb = b & 31; }
  else               { proj = 2; b -= 192; h = b >> 5; rb = b & 31; }
  const float* x = (proj == 0) ? xQ : xK;
  const float* W = (proj == 0 ? Wq : (proj == 1 ? Wk : Wv)) + (size_t)h * 256 * 64;

  for (int i = threadIdx.x; i < 16384; i += 256)
    Wt[i & 63][i >> 6] = f2bf(W[i]);
  __syncthreads();

  int lane = threadIdx.x & 63, wv = threadIdx.x >> 6;
  int quad = lane >> 4, n16 = lane & 15;
  int r0 = rb * 256 + wv * 64;

  f32x4 acc[4][4];
#pragma unroll
  for (int mt = 0; mt < 4; ++mt)
#pragma unroll
    for (int nt = 0; nt < 4; ++nt)
      acc[mt][nt] = (f32x4){0.f, 0.f, 0.f, 0.f};

#pragma unroll
  for (int it = 0; it < 8; ++it) {
    const int k0 = it * 32;
    bf16x8 af[4];
#pragma unroll
    for (int mt = 0; mt < 4; ++mt) {
      const float* xp = x + (size_t)(r0 + mt * 16 + n16) * 256 + k0 + quad * 8;
      const float4 a0 = *(const float4*)xp;
      const float4 a1 = *(const float4*)(xp + 4);
      bf16x8 a;
      a[0] = (short)f2bf(a0.x); a[1] = (short)f2bf(a0.y);
      a[2] = (short)f2bf(a0.z); a[3] = (short)f2bf(a0.w);
      a[4] = (short)f2bf(a1.x); a[5] = (short)f2bf(a1.y);
      a[6] = (short)f2bf(a1.z); a[7] = (short)f2bf(a1.w);
      af[mt] = a;
    }
    bf16x8 bfr[4];
#pragma unroll
    for (int nt = 0; nt < 4; ++nt)
      bfr[nt] = *(const bf16x8*)&Wt[nt * 16 + n16][k0 + quad * 8];
#pragma unroll
    for (int mt = 0; mt < 4; ++mt)
#pragma unroll
      for (int nt = 0; nt < 4; ++nt)
        acc[mt][nt] = __builtin_amdgcn_mfma_f32_16x16x32_bf16(
            af[mt], bfr[nt], acc[mt][nt], 0, 0, 0);
  }

  if (proj < 2) {
    unsigned short* outp =
        (proj == 0 ? Qp : Kp) + (size_t)h * (size_t)(proj == 0 ? NQ : NK) * 64;
    const float sc = (proj == 0) ? QSCALE : 1.0f;
#pragma unroll
    for (int mt = 0; mt < 4; ++mt)
#pragma unroll
      for (int nt = 0; nt < 4; ++nt)
#pragma unroll
        for (int r = 0; r < 4; ++r) {
          int row = r0 + mt * 16 + quad * 4 + r;
          int col = nt * 16 + n16;
          outp[(size_t)row * 64 + col] = f2bf(acc[mt][nt][r] * sc);
        }
  } else {
    // fragment-linear V: tile = h*256 + keyblock32; within tile:
    // ((kr*4 + dt)*64 + lane)*4 f16, lane's 4 = keys quad*4+r of d-row n16
#pragma unroll
    for (int mt = 0; mt < 4; ++mt) {
      int tile = h * 256 + ((r0 + mt * 16) >> 5);
      int kr = mt & 1;
#pragma unroll
      for (int nt = 0; nt < 4; ++nt) {
        f16x4 pk;
        pk[0] = (_Float16)acc[mt][nt][0]; pk[1] = (_Float16)acc[mt][nt][1];
        pk[2] = (_Float16)acc[mt][nt][2]; pk[3] = (_Float16)acc[mt][nt][3];
        *(f16x4*)&Vf[(((size_t)tile * 8 + kr * 4 + nt) * 64 + lane) * 4] = pk;
      }
    }
  }
}

// ---------------------------------------------------------------------------
// 3. flash attention, S^T formulation, fixed max, in-register P (no LDS in
//    the K-loop). Block = 4 waves = 4 adjacent key-splits of ONE (h, qtile);
//    end-of-kernel LDS reduction collapses them -> Opart is 4x smaller and
//    combine reads coalesce. V loads are fragment-linear 512B; bits loads
//    are 64B contiguous (transposed layout).
// ---------------------------------------------------------------------------
__global__ __launch_bounds__(256, 6) void attn_kernel(
    const unsigned short* __restrict__ Qp, const unsigned short* __restrict__ Kp,
    const _Float16* __restrict__ Vf, const unsigned* __restrict__ bitsT,
    _Float16* __restrict__ Opart, float* __restrict__ Lpart) {
  __shared__ __align__(16) float Ob[32][68];   // +4 pad: conflict-free cols
  __shared__ float Lb[32];

  int b = blockIdx.x;
  int ksg = b & 3, h = (b >> 2) & 3, qt = b >> 4;
  int wv = threadIdx.x >> 6, lane = threadIdx.x & 63;
  int quad = lane >> 4, n16 = lane & 15;
  int ks = ksg * 4 + wv;          // this wave's key-split (of 16)
  int qb = qt * 32;

  // Q frags (bf16, pre-scaled by QSCALE)
  bf16x8 qf[2][2];
#pragma unroll
  for (int qc = 0; qc < 2; ++qc)
#pragma unroll
    for (int c = 0; c < 2; ++c)
      qf[qc][c] = *(const bf16x8*)&Qp[((size_t)h * NQ + qb + qc * 16 + n16) * 64 +
                                      c * 32 + quad * 8];

  f32x4 o[4][2];
#pragma unroll
  for (int dt = 0; dt < 4; ++dt)
#pragma unroll
    for (int qc = 0; qc < 2; ++qc) o[dt][qc] = (f32x4){0.f, 0.f, 0.f, 0.f};
  float ls[2] = {0.f, 0.f};

  const unsigned short* Kptr =
      Kp + (size_t)h * NK * 64 + (size_t)(ks * KLEN + n16) * 64 + quad * 8;
  const _Float16* Vbase = Vf + ((size_t)h * 256 + ks * 16) * 2048 + lane * 4;
  const unsigned* bT = bitsT + (size_t)(ks * 16) * NQ + qb;

#pragma unroll 2
  for (int kb = 0; kb < KLEN / 32; ++kb) {
    unsigned wqa0 = bT[(size_t)kb * NQ + n16];
    unsigned wqa1 = bT[(size_t)kb * NQ + 16 + n16];

    // K A-frags (bf16, K=32): rows = keys, 64B segments
    const unsigned short* Kg = Kptr + (size_t)kb * 32 * 64;
    bf16x8 kf[2][2];
#pragma unroll
    for (int kr = 0; kr < 2; ++kr)
#pragma unroll
      for (int c = 0; c < 2; ++c)
        kf[kr][c] = *(const bf16x8*)(Kg + kr * 16 * 64 + c * 32);

    // V A-frags: fragment-linear, 512B contiguous per (kr,dt)
    const _Float16* Vg = Vbase + (size_t)kb * 2048;
    f16x4 vf[4][2];
#pragma unroll
    for (int kr = 0; kr < 2; ++kr)
#pragma unroll
      for (int dt = 0; dt < 4; ++dt)
        vf[dt][kr] = *(const f16x4*)(Vg + (kr * 4 + dt) * 256);

    // S^T = K·Q^T (bf16 K=32, pre-scaled)
    f32x4 s[2][2];
#pragma unroll
    for (int kr = 0; kr < 2; ++kr)
#pragma unroll
      for (int qc = 0; qc < 2; ++qc) {
        f32x4 acc = (f32x4){0.f, 0.f, 0.f, 0.f};
        acc = __builtin_amdgcn_mfma_f32_16x16x32_bf16(kf[kr][0], qf[qc][0], acc, 0, 0, 0);
        acc = __builtin_amdgcn_mfma_f32_16x16x32_bf16(kf[kr][1], qf[qc][1], acc, 0, 0, 0);
        s[kr][qc] = acc;
      }

    // P = exp2(S^T) masked -> f16 B-frags in-register (B-layout == C/D layout
    // for K=16 f16 MFMA), plus l partial sums
#pragma unroll
    for (int qc = 0; qc < 2; ++qc) {
      unsigned wq = (qc == 0 ? wqa0 : wqa1) >> (quad * 4);
      f16x4 pf[2];
#pragma unroll
      for (int kr = 0; kr < 2; ++kr) {
        float e0 = __builtin_amdgcn_exp2f(s[kr][qc][0]);
        float e1 = __builtin_amdgcn_exp2f(s[kr][qc][1]);
        float e2 = __builtin_amdgcn_exp2f(s[kr][qc][2]);
        float e3 = __builtin_amdgcn_exp2f(s[kr][qc][3]);
        e0 = (wq & (1u << (kr * 16 + 0))) ? e0 : 0.f;
        e1 = (wq & (1u << (kr * 16 + 1))) ? e1 : 0.f;
        e2 = (wq & (1u << (kr * 16 + 2))) ? e2 : 0.f;
        e3 = (wq & (1u << (kr * 16 + 3))) ? e3 : 0.f;
        ls[qc] += (e0 + e1) + (e2 + e3);
        f16x4 p;
        p[0] = (_Float16)e0; p[1] = (_Float16)e1;
        p[2] = (_Float16)e2; p[3] = (_Float16)e3;
        pf[kr] = p;
      }
#pragma unroll
      for (int dt = 0; dt < 4; ++dt) {
        o[dt][qc] = __builtin_amdgcn_mfma_f32_16x16x16f16(vf[dt][0], pf[0],
                                                          o[dt][qc], 0, 0, 0);
        o[dt][qc] = __builtin_amdgcn_mfma_f32_16x16x16f16(vf[dt][1], pf[1],
                                                          o[dt][qc], 0, 0, 0);
      }
    }
  }

  // l: reduce across quads (each lane holds partials over its keys)
#pragma unroll
  for (int qc = 0; qc < 2; ++qc) {
    ls[qc] += __shfl_xor(ls[qc], 16);
    ls[qc] += __shfl_xor(ls[qc], 32);
  }

  // ---- in-block reduction over the 4 splits (sequential barriered phases)
#pragma unroll
  for (int w = 0; w < 4; ++w) {
    if (wv == w) {
      if (w == 0) {
#pragma unroll
        for (int qc = 0; qc < 2; ++qc)
#pragma unroll
          for (int dt = 0; dt < 4; ++dt)
            *(f32x4*)&Ob[qc * 16 + n16][dt * 16 + quad * 4] = o[dt][qc];
        if (quad == 0) { Lb[n16] = ls[0]; Lb[16 + n16] = ls[1]; }
      } else {
#pragma unroll
        for (int qc = 0; qc < 2; ++qc)
#pragma unroll
          for (int dt = 0; dt < 4; ++dt) {
            f32x4 t = *(f32x4*)&Ob[qc * 16 + n16][dt * 16 + quad * 4];
            t += o[dt][qc];
            *(f32x4*)&Ob[qc * 16 + n16][dt * 16 + quad * 4] = t;
          }
        if (quad == 0) { Lb[n16] += ls[0]; Lb[16 + n16] += ls[1]; }
      }
    }
    __syncthreads();
  }

  // cooperative coalesced store: tile = (h*NQT+qt)*NSUP + ksg
  const size_t tile = ((size_t)h * NQT + qt) * NSUP + ksg;
  {
    int tid = threadIdx.x;
    int r = tid >> 3, c0 = (tid & 7) * 8;
    f32x4 a = *(f32x4*)&Ob[r][c0];
    f32x4 b2 = *(f32x4*)&Ob[r][c0 + 4];
    f16x8 ov;
    ov[0] = (_Float16)a[0]; ov[1] = (_Float16)a[1];
    ov[2] = (_Float16)a[2]; ov[3] = (_Float16)a[3];
    ov[4] = (_Float16)b2[0]; ov[5] = (_Float16)b2[1];
    ov[6] = (_Float16)b2[2]; ov[7] = (_Float16)b2[3];
    *(f16x8*)&Opart[(tile * 32 + r) * 64 + c0] = ov;
    if (tid < 32) Lpart[tile * 32 + tid] = Lb[tid];
  }
}

// ---------------------------------------------------------------------------
// 4. combine NSUP partials + fused gates + @Wo + bo. 256 blocks x 16 rows
// ---------------------------------------------------------------------------
__global__ __launch_bounds__(256) void combine_kernel(
    const _Float16* __restrict__ Opart, const float* __restrict__ Lpart,
    const float* __restrict__ xQ, const float* __restrict__ Wg,
    const float* __restrict__ bg, const float* __restrict__ Wo,
    const float* __restrict__ bo, float* __restrict__ out) {
  __shared__ float comb[16][64];
  __shared__ float gred[16][4][4];
  __shared__ float glds[16][4];
  int nb = blockIdx.x;
  int tid = threadIdx.x;

  // gates for this block's 16 rows
  {
    int r = tid >> 4, hh = (tid >> 2) & 3, c = tid & 3;
    const float* xp = xQ + (size_t)(nb * 16 + r) * 256 + c * 64;
    const float* wp = Wg + hh * 256 + c * 64;
    float s = 0.f;
#pragma unroll
    for (int e = 0; e < 64; ++e) s = fmaf(xp[e], wp[e], s);
    gred[r][hh][c] = s;
  }
  __syncthreads();
  if (tid < 64) {
    int r = tid >> 2, hh = tid & 3;
    float s = gred[r][hh][0] + gred[r][hh][1] + gred[r][hh][2] + gred[r][hh][3];
    glds[r][hh] = 1.f / (1.f + __expf(-(s + bg[hh])));
  }
  __syncthreads();

  int r4 = tid >> 6, a = tid & 63;
  int qt = nb >> 1, rbase = (nb & 1) * 16;

  for (int p = 0; p < 4; ++p) {
    int r = p * 4 + r4;
    int rl = rbase + r;
    float csum = 0.f;
#pragma unroll
    for (int h = 0; h < NH; ++h) {
      size_t t0 = ((size_t)h * NQT + qt) * NSUP;
      float accO = 0.f, lt = 0.f;
#pragma unroll
      for (int s = 0; s < NSUP; ++s) {
        size_t t = t0 + s;
        accO += (float)Opart[(t * 32 + rl) * 64 + a];
        lt += Lpart[t * 32 + rl];
      }
      csum += glds[r][h] * accO / lt;
    }
    comb[r][a] = csum;
  }
  __syncthreads();

  int j = tid;
  float accv[16];
#pragma unroll
  for (int r = 0; r < 16; ++r) accv[r] = bo[j];
  for (int aa = 0; aa < 64; ++aa) {
    float w = Wo[(size_t)aa * 256 + j];
#pragma unroll
    for (int r = 0; r < 16; ++r) accv[r] = fmaf(comb[r][aa], w, accv[r]);
  }
#pragma unroll
  for (int r = 0; r < 16; ++r)
    out[(size_t)(nb * 16 + r) * 256 + j] = accv[r];
}

// ---------------------------------------------------------------------------
extern "C" void kernel_launch(void* const* d_in, const int* in_sizes, int n_in,
                              void* d_out, int out_size, void* d_ws, size_t ws_size,
                              hipStream_t stream) {
  const float* xQ  = (const float*)d_in[0];
  const float* xK  = (const float*)d_in[1];
  const int*   mask= (const int*)d_in[2];
  const float* Wq  = (const float*)d_in[3];
  const float* Wk  = (const float*)d_in[4];
  const float* Wv  = (const float*)d_in[5];
  const float* Wg  = (const float*)d_in[6];
  const float* bg  = (const float*)d_in[7];
  const float* Wo  = (const float*)d_in[8];
  const float* bo  = (const float*)d_in[9];
  float* out = (float*)d_out;

  char* ws = (char*)d_ws;
  unsigned short* Qp   = (unsigned short*)(ws + 0);         // 2 MB  [H][NQ][64]
  unsigned short* Kp   = (unsigned short*)(ws + 2097152);   // 4 MB  [H][NK][64]
  _Float16*       Vfp  = (_Float16*)(ws + 6291456);         // 4 MB  frag-linear
  unsigned*       bitsT= (unsigned*)(ws + 10485760);        // 4 MB  [word][row]
  float*          Lp   = (float*)(ws + 14680064);           // 256 KB
  _Float16*       Op   = (_Float16*)(ws + 14942208);        // 8.4 MB f16

  maskbits_kernel<<<dim3(8192), dim3(256), 0, stream>>>(mask, bitsT);
  proj_kernel<<<dim3(320), dim3(256), 0, stream>>>(xQ, xK, Wq, Wk, Wv, Qp, Kp, Vfp);
  attn_kernel<<<dim3(2048), dim3(256), 0, stream>>>(Qp, Kp, Vfp, bitsT, Op, Lp);
  combine_kernel<<<dim3(NQ / 16), dim3(256), 0, stream>>>(Op, Lp, xQ, Wg, bg,
                                                          Wo, bo, out);
}

// Round 7
// 358.227 us; speedup vs baseline: 1.7317x; 1.7317x over previous
//
#include <hip/hip_runtime.h>
#include <hip/hip_bf16.h>

#define NQ 4096
#define NK 8192
#define DQK 256
#define DA 64
#define NH 4
#define DOUT 256
#define KSPLIT 16
#define KLEN (NK / KSPLIT)   // 512 keys per split
#define NQT (NQ / 32)        // 128 q-tiles of 32
#define NSUP 4               // split-groups surviving to combine (16/4 waves)
#define LOG2E 1.44269504088896340736f
#define QSCALE (0.125f * LOG2E)   // 1/sqrt(64) * log2(e), folded into Qp

typedef __attribute__((ext_vector_type(8))) short bf16x8;
typedef __attribute__((ext_vector_type(4))) float f32x4;
typedef __attribute__((ext_vector_type(4))) _Float16 f16x4;
typedef __attribute__((ext_vector_type(8))) _Float16 f16x8;

__device__ inline unsigned short f2bf(float f) {
  union { float f; unsigned u; } v; v.f = f;
  unsigned r = v.u + 0x7fff + ((v.u >> 16) & 1);  // RNE
  return (unsigned short)(r >> 16);
}

// ---------------------------------------------------------------------------
// 1. mask (int32 NQ x NK) -> TRANSPOSED bitmask bitsT[word32][row] (4 MB).
//    attn then reads 16 consecutive rows' words as one 64B segment.
// ---------------------------------------------------------------------------
__global__ __launch_bounds__(256) void maskbits_kernel(
    const int* __restrict__ mask, unsigned* __restrict__ bitsT) {
  const int NW = 8192 * 4;                       // total waves
  int wid = blockIdx.x * 4 + (threadIdx.x >> 6);
  int lane = threadIdx.x & 63;
  for (int j = 0; j < 2; ++j) {
    int v[8];
#pragma unroll
    for (int u = 0; u < 8; ++u) {
      int c = wid + (j * 8 + u) * NW;   // u64 chunk id: row = c>>7, ch = c&127
      v[u] = mask[(size_t)(c >> 7) * NK + (c & 127) * 64 + lane];
    }
#pragma unroll
    for (int u = 0; u < 8; ++u) {
      unsigned long long b = __ballot(v[u] != 0);
      int c = wid + (j * 8 + u) * NW;
      int n = c >> 7, ch = c & 127;
      if (lane == 0)  bitsT[(size_t)(2 * ch) * NQ + n] = (unsigned)b;
      if (lane == 32) bitsT[(size_t)(2 * ch + 1) * NQ + n] = (unsigned)(b >> 32);
    }
  }
}

// ---------------------------------------------------------------------------
// 2. projections: Q = xQ@Wq[h] * QSCALE -> Qp[h][n][d] bf16 (scale folded)
//                 K = xK@Wk[h] -> Kp[h][m][d] bf16
//                 V -> Vf f16 in MFMA A-FRAGMENT-LINEAR order: the proj
//                 accumulator lane content (4 consecutive keys of one d,
//                 lane = quad*16+n16) IS the PV A-frag, so store it
//                 contiguously per (tile32,kr,dt): 512B coalesced stores,
//                 512B coalesced loads in attn.
// ---------------------------------------------------------------------------
__global__ __launch_bounds__(256) void proj_kernel(
    const float* __restrict__ xQ, const float* __restrict__ xK,
    const float* __restrict__ Wq, const float* __restrict__ Wk,
    const float* __restrict__ Wv,
    unsigned short* __restrict__ Qp, unsigned short* __restrict__ Kp,
    _Float16* __restrict__ Vf) {
  __shared__ __align__(16) unsigned short Wt[64][264];  // Wt[d][c], padded

  int b = blockIdx.x;
  int proj, h, rb;
  if (b < 64)        { proj = 0; h = b >> 4;  rb = b & 15; }
  else if (b < 192)  { proj = 1; b -= 64;  h = b >> 5; rb = b & 31; }
  else               { proj = 2; b -= 192; h = b >> 5; rb = b & 31; }
  const float* x = (proj == 0) ? xQ : xK;
  const float* W = (proj == 0 ? Wq : (proj == 1 ? Wk : Wv)) + (size_t)h * 256 * 64;

  for (int i = threadIdx.x; i < 16384; i += 256)
    Wt[i & 63][i >> 6] = f2bf(W[i]);
  __syncthreads();

  int lane = threadIdx.x & 63, wv = threadIdx.x >> 6;
  int quad = lane >> 4, n16 = lane & 15;
  int r0 = rb * 256 + wv * 64;

  f32x4 acc[4][4];
#pragma unroll
  for (int mt = 0; mt < 4; ++mt)
#pragma unroll
    for (int nt = 0; nt < 4; ++nt)
      acc[mt][nt] = (f32x4){0.f, 0.f, 0.f, 0.f};

#pragma unroll
  for (int it = 0; it < 8; ++it) {
    const int k0 = it * 32;
    bf16x8 af[4];
#pragma unroll
    for (int mt = 0; mt < 4; ++mt) {
      const float* xp = x + (size_t)(r0 + mt * 16 + n16) * 256 + k0 + quad * 8;
      const float4 a0 = *(const float4*)xp;
      const float4 a1 = *(const float4*)(xp + 4);
      bf16x8 a;
      a[0] = (short)f2bf(a0.x); a[1] = (short)f2bf(a0.y);
      a[2] = (short)f2bf(a0.z); a[3] = (short)f2bf(a0.w);
      a[4] = (short)f2bf(a1.x); a[5] = (short)f2bf(a1.y);
      a[6] = (short)f2bf(a1.z); a[7] = (short)f2bf(a1.w);
      af[mt] = a;
    }
    bf16x8 bfr[4];
#pragma unroll
    for (int nt = 0; nt < 4; ++nt)
      bfr[nt] = *(const bf16x8*)&Wt[nt * 16 + n16][k0 + quad * 8];
#pragma unroll
    for (int mt = 0; mt < 4; ++mt)
#pragma unroll
      for (int nt = 0; nt < 4; ++nt)
        acc[mt][nt] = __builtin_amdgcn_mfma_f32_16x16x32_bf16(
            af[mt], bfr[nt], acc[mt][nt], 0, 0, 0);
  }

  if (proj < 2) {
    unsigned short* outp =
        (proj == 0 ? Qp : Kp) + (size_t)h * (size_t)(proj == 0 ? NQ : NK) * 64;
    const float sc = (proj == 0) ? QSCALE : 1.0f;
#pragma unroll
    for (int mt = 0; mt < 4; ++mt)
#pragma unroll
      for (int nt = 0; nt < 4; ++nt)
#pragma unroll
        for (int r = 0; r < 4; ++r) {
          int row = r0 + mt * 16 + quad * 4 + r;
          int col = nt * 16 + n16;
          outp[(size_t)row * 64 + col] = f2bf(acc[mt][nt][r] * sc);
        }
  } else {
    // fragment-linear V: tile = h*256 + keyblock32; within tile:
    // ((kr*4 + dt)*64 + lane)*4 f16, lane's 4 = keys quad*4+r of d-row n16
#pragma unroll
    for (int mt = 0; mt < 4; ++mt) {
      int tile = h * 256 + ((r0 + mt * 16) >> 5);
      int kr = mt & 1;
#pragma unroll
      for (int nt = 0; nt < 4; ++nt) {
        f16x4 pk;
        pk[0] = (_Float16)acc[mt][nt][0]; pk[1] = (_Float16)acc[mt][nt][1];
        pk[2] = (_Float16)acc[mt][nt][2]; pk[3] = (_Float16)acc[mt][nt][3];
        *(f16x4*)&Vf[(((size_t)tile * 8 + kr * 4 + nt) * 64 + lane) * 4] = pk;
      }
    }
  }
}

// ---------------------------------------------------------------------------
// 3. flash attention, S^T formulation, fixed max, in-register P (no LDS in
//    the K-loop). Block = 4 waves = 4 adjacent key-splits of ONE (h, qtile);
//    end-of-kernel LDS reduction collapses them. V loads fragment-linear
//    512B; bits loads 64B contiguous.
//    __launch_bounds__(256, 4): 128-VGPR budget fits the ~100-reg live set
//    with ZERO spill (the (256,6) hint forced scratch spills: 1.5 GB/launch).
// ---------------------------------------------------------------------------
__global__ __launch_bounds__(256, 4) void attn_kernel(
    const unsigned short* __restrict__ Qp, const unsigned short* __restrict__ Kp,
    const _Float16* __restrict__ Vf, const unsigned* __restrict__ bitsT,
    _Float16* __restrict__ Opart, float* __restrict__ Lpart) {
  __shared__ __align__(16) float Ob[32][68];   // +4 pad: conflict-free cols
  __shared__ float Lb[32];

  int b = blockIdx.x;
  int ksg = b & 3, h = (b >> 2) & 3, qt = b >> 4;
  int wv = threadIdx.x >> 6, lane = threadIdx.x & 63;
  int quad = lane >> 4, n16 = lane & 15;
  int ks = ksg * 4 + wv;          // this wave's key-split (of 16)
  int qb = qt * 32;

  // Q frags (bf16, pre-scaled by QSCALE)
  bf16x8 qf[2][2];
#pragma unroll
  for (int qc = 0; qc < 2; ++qc)
#pragma unroll
    for (int c = 0; c < 2; ++c)
      qf[qc][c] = *(const bf16x8*)&Qp[((size_t)h * NQ + qb + qc * 16 + n16) * 64 +
                                      c * 32 + quad * 8];

  f32x4 o[4][2];
#pragma unroll
  for (int dt = 0; dt < 4; ++dt)
#pragma unroll
    for (int qc = 0; qc < 2; ++qc) o[dt][qc] = (f32x4){0.f, 0.f, 0.f, 0.f};
  float ls[2] = {0.f, 0.f};

  const unsigned short* Kptr =
      Kp + (size_t)h * NK * 64 + (size_t)(ks * KLEN + n16) * 64 + quad * 8;
  const _Float16* Vbase = Vf + ((size_t)h * 256 + ks * 16) * 2048 + lane * 4;
  const unsigned* bT = bitsT + (size_t)(ks * 16) * NQ + qb;

#pragma unroll 2
  for (int kb = 0; kb < KLEN / 32; ++kb) {
    unsigned wqa0 = bT[(size_t)kb * NQ + n16];
    unsigned wqa1 = bT[(size_t)kb * NQ + 16 + n16];

    // K A-frags (bf16, K=32): rows = keys, 64B segments
    const unsigned short* Kg = Kptr + (size_t)kb * 32 * 64;
    bf16x8 kf[2][2];
#pragma unroll
    for (int kr = 0; kr < 2; ++kr)
#pragma unroll
      for (int c = 0; c < 2; ++c)
        kf[kr][c] = *(const bf16x8*)(Kg + kr * 16 * 64 + c * 32);

    // V A-frags: fragment-linear, 512B contiguous per (kr,dt)
    const _Float16* Vg = Vbase + (size_t)kb * 2048;
    f16x4 vf[4][2];
#pragma unroll
    for (int kr = 0; kr < 2; ++kr)
#pragma unroll
      for (int dt = 0; dt < 4; ++dt)
        vf[dt][kr] = *(const f16x4*)(Vg + (kr * 4 + dt) * 256);

    // S^T = K·Q^T (bf16 K=32, pre-scaled)
    f32x4 s[2][2];
#pragma unroll
    for (int kr = 0; kr < 2; ++kr)
#pragma unroll
      for (int qc = 0; qc < 2; ++qc) {
        f32x4 acc = (f32x4){0.f, 0.f, 0.f, 0.f};
        acc = __builtin_amdgcn_mfma_f32_16x16x32_bf16(kf[kr][0], qf[qc][0], acc, 0, 0, 0);
        acc = __builtin_amdgcn_mfma_f32_16x16x32_bf16(kf[kr][1], qf[qc][1], acc, 0, 0, 0);
        s[kr][qc] = acc;
      }

    // P = exp2(S^T) masked -> f16 B-frags in-register (B-layout == C/D layout
    // for K=16 f16 MFMA), plus l partial sums
#pragma unroll
    for (int qc = 0; qc < 2; ++qc) {
      unsigned wq = (qc == 0 ? wqa0 : wqa1) >> (quad * 4);
      f16x4 pf[2];
#pragma unroll
      for (int kr = 0; kr < 2; ++kr) {
        float e0 = __builtin_amdgcn_exp2f(s[kr][qc][0]);
        float e1 = __builtin_amdgcn_exp2f(s[kr][qc][1]);
        float e2 = __builtin_amdgcn_exp2f(s[kr][qc][2]);
        float e3 = __builtin_amdgcn_exp2f(s[kr][qc][3]);
        e0 = (wq & (1u << (kr * 16 + 0))) ? e0 : 0.f;
        e1 = (wq & (1u << (kr * 16 + 1))) ? e1 : 0.f;
        e2 = (wq & (1u << (kr * 16 + 2))) ? e2 : 0.f;
        e3 = (wq & (1u << (kr * 16 + 3))) ? e3 : 0.f;
        ls[qc] += (e0 + e1) + (e2 + e3);
        f16x4 p;
        p[0] = (_Float16)e0; p[1] = (_Float16)e1;
        p[2] = (_Float16)e2; p[3] = (_Float16)e3;
        pf[kr] = p;
      }
#pragma unroll
      for (int dt = 0; dt < 4; ++dt) {
        o[dt][qc] = __builtin_amdgcn_mfma_f32_16x16x16f16(vf[dt][0], pf[0],
                                                          o[dt][qc], 0, 0, 0);
        o[dt][qc] = __builtin_amdgcn_mfma_f32_16x16x16f16(vf[dt][1], pf[1],
                                                          o[dt][qc], 0, 0, 0);
      }
    }
  }

  // l: reduce across quads (each lane holds partials over its keys)
#pragma unroll
  for (int qc = 0; qc < 2; ++qc) {
    ls[qc] += __shfl_xor(ls[qc], 16);
    ls[qc] += __shfl_xor(ls[qc], 32);
  }

  // ---- in-block reduction over the 4 splits (sequential barriered phases)
#pragma unroll
  for (int w = 0; w < 4; ++w) {
    if (wv == w) {
      if (w == 0) {
#pragma unroll
        for (int qc = 0; qc < 2; ++qc)
#pragma unroll
          for (int dt = 0; dt < 4; ++dt)
            *(f32x4*)&Ob[qc * 16 + n16][dt * 16 + quad * 4] = o[dt][qc];
        if (quad == 0) { Lb[n16] = ls[0]; Lb[16 + n16] = ls[1]; }
      } else {
#pragma unroll
        for (int qc = 0; qc < 2; ++qc)
#pragma unroll
          for (int dt = 0; dt < 4; ++dt) {
            f32x4 t = *(f32x4*)&Ob[qc * 16 + n16][dt * 16 + quad * 4];
            t += o[dt][qc];
            *(f32x4*)&Ob[qc * 16 + n16][dt * 16 + quad * 4] = t;
          }
        if (quad == 0) { Lb[n16] += ls[0]; Lb[16 + n16] += ls[1]; }
      }
    }
    __syncthreads();
  }

  // cooperative coalesced store: tile = (h*NQT+qt)*NSUP + ksg
  const size_t tile = ((size_t)h * NQT + qt) * NSUP + ksg;
  {
    int tid = threadIdx.x;
    int r = tid >> 3, c0 = (tid & 7) * 8;
    f32x4 a = *(f32x4*)&Ob[r][c0];
    f32x4 b2 = *(f32x4*)&Ob[r][c0 + 4];
    f16x8 ov;
    ov[0] = (_Float16)a[0]; ov[1] = (_Float16)a[1];
    ov[2] = (_Float16)a[2]; ov[3] = (_Float16)a[3];
    ov[4] = (_Float16)b2[0]; ov[5] = (_Float16)b2[1];
    ov[6] = (_Float16)b2[2]; ov[7] = (_Float16)b2[3];
    *(f16x8*)&Opart[(tile * 32 + r) * 64 + c0] = ov;
    if (tid < 32) Lpart[tile * 32 + tid] = Lb[tid];
  }
}

// ---------------------------------------------------------------------------
// 4. combine NSUP partials + fused gates + @Wo + bo. 256 blocks x 16 rows
// ---------------------------------------------------------------------------
__global__ __launch_bounds__(256) void combine_kernel(
    const _Float16* __restrict__ Opart, const float* __restrict__ Lpart,
    const float* __restrict__ xQ, const float* __restrict__ Wg,
    const float* __restrict__ bg, const float* __restrict__ Wo,
    const float* __restrict__ bo, float* __restrict__ out) {
  __shared__ float comb[16][64];
  __shared__ float gred[16][4][4];
  __shared__ float glds[16][4];
  int nb = blockIdx.x;
  int tid = threadIdx.x;

  // gates for this block's 16 rows
  {
    int r = tid >> 4, hh = (tid >> 2) & 3, c = tid & 3;
    const float* xp = xQ + (size_t)(nb * 16 + r) * 256 + c * 64;
    const float* wp = Wg + hh * 256 + c * 64;
    float s = 0.f;
#pragma unroll
    for (int e = 0; e < 64; ++e) s = fmaf(xp[e], wp[e], s);
    gred[r][hh][c] = s;
  }
  __syncthreads();
  if (tid < 64) {
    int r = tid >> 2, hh = tid & 3;
    float s = gred[r][hh][0] + gred[r][hh][1] + gred[r][hh][2] + gred[r][hh][3];
    glds[r][hh] = 1.f / (1.f + __expf(-(s + bg[hh])));
  }
  __syncthreads();

  int r4 = tid >> 6, a = tid & 63;
  int qt = nb >> 1, rbase = (nb & 1) * 16;

  for (int p = 0; p < 4; ++p) {
    int r = p * 4 + r4;
    int rl = rbase + r;
    float csum = 0.f;
#pragma unroll
    for (int h = 0; h < NH; ++h) {
      size_t t0 = ((size_t)h * NQT + qt) * NSUP;
      float accO = 0.f, lt = 0.f;
#pragma unroll
      for (int s = 0; s < NSUP; ++s) {
        size_t t = t0 + s;
        accO += (float)Opart[(t * 32 + rl) * 64 + a];
        lt += Lpart[t * 32 + rl];
      }
      csum += glds[r][h] * accO / lt;
    }
    comb[r][a] = csum;
  }
  __syncthreads();

  int j = tid;
  float accv[16];
#pragma unroll
  for (int r = 0; r < 16; ++r) accv[r] = bo[j];
  for (int aa = 0; aa < 64; ++aa) {
    float w = Wo[(size_t)aa * 256 + j];
#pragma unroll
    for (int r = 0; r < 16; ++r) accv[r] = fmaf(comb[r][aa], w, accv[r]);
  }
#pragma unroll
  for (int r = 0; r < 16; ++r)
    out[(size_t)(nb * 16 + r) * 256 + j] = accv[r];
}

// ---------------------------------------------------------------------------
extern "C" void kernel_launch(void* const* d_in, const int* in_sizes, int n_in,
                              void* d_out, int out_size, void* d_ws, size_t ws_size,
                              hipStream_t stream) {
  const float* xQ  = (const float*)d_in[0];
  const float* xK  = (const float*)d_in[1];
  const int*   mask= (const int*)d_in[2];
  const float* Wq  = (const float*)d_in[3];
  const float* Wk  = (const float*)d_in[4];
  const float* Wv  = (const float*)d_in[5];
  const float* Wg  = (const float*)d_in[6];
  const float* bg  = (const float*)d_in[7];
  const float* Wo  = (const float*)d_in[8];
  const float* bo  = (const float*)d_in[9];
  float* out = (float*)d_out;

  char* ws = (char*)d_ws;
  unsigned short* Qp   = (unsigned short*)(ws + 0);         // 2 MB  [H][NQ][64]
  unsigned short* Kp   = (unsigned short*)(ws + 2097152);   // 4 MB  [H][NK][64]
  _Float16*       Vfp  = (_Float16*)(ws + 6291456);         // 4 MB  frag-linear
  unsigned*       bitsT= (unsigned*)(ws + 10485760);        // 4 MB  [word][row]
  float*          Lp   = (float*)(ws + 14680064);           // 256 KB
  _Float16*       Op   = (_Float16*)(ws + 14942208);        // 8.4 MB f16

  maskbits_kernel<<<dim3(8192), dim3(256), 0, stream>>>(mask, bitsT);
  proj_kernel<<<dim3(320), dim3(256), 0, stream>>>(xQ, xK, Wq, Wk, Wv, Qp, Kp, Vfp);
  attn_kernel<<<dim3(2048), dim3(256), 0, stream>>>(Qp, Kp, Vfp, bitsT, Op, Lp);
  combine_kernel<<<dim3(NQ / 16), dim3(256), 0, stream>>>(Op, Lp, xQ, Wg, bg,
                                                          Wo, bo, out);
}